// Round 3
// baseline (853.109 us; speedup 1.0000x reference)
//
#include <hip/hip_runtime.h>
#include <math.h>

// ---- problem constants ----
#define TB        256           // threads per block = 4 waves
#define POSB      256           // positions per block = 1 per THREAD
#define NPOS      131072        // B*H*W positions
#define KCODES    512
#define DIM       64
#define HW        4096          // H*W
#define LOSS_OFF  8388608ull
#define ENC_OFF   8388609ull
#define PERP_OFF  75497473ull
#define TILE_DW   (POSB * KCODES)       // 131072 dwords: block's encodings tile
#define NF4       ((TILE_DW - 4) / 4)   // 32767 float4 after the +3 align shift

__device__ __forceinline__ float tree8(float r0, float r1, float r2, float r3,
                                       float r4, float r5, float r6, float r7) {
    // numpy pairwise combine: ((r0+r1)+(r2+r3)) + ((r4+r5)+(r6+r7))
    return __fadd_rn(__fadd_rn(__fadd_rn(r0, r1), __fadd_rn(r2, r3)),
                     __fadd_rn(__fadd_rn(r4, r5), __fadd_rn(r6, r7)));
}

// constant-index float4 component select (folds after unroll; no address taken)
#define F4C(q, c) ((c) == 0 ? (q).x : (c) == 1 ? (q).y : (c) == 2 ? (q).z : (q).w)

// Prep: ww[k] = sum(w[k]^2) in numpy pairwise order; zero counts + loss accumulator.
extern "C" __global__ __launch_bounds__(512)
void vq_prep(const float* __restrict__ w, float* __restrict__ ww,
             int* __restrict__ counts, float* __restrict__ lossAcc)
{
    const int k = threadIdx.x;                 // 512 threads
    const float* wk = w + k * DIM;
    float r[8];
    #pragma unroll
    for (int i = 0; i < 8; ++i) {
        #pragma unroll
        for (int j = 0; j < 8; ++j) {
            float v = wk[i * 8 + j];
            float pp = __fmul_rn(v, v);
            r[j] = (i == 0) ? pp : __fadd_rn(r[j], pp);
        }
    }
    ww[k] = tree8(r[0], r[1], r[2], r[3], r[4], r[5], r[6], r[7]);
    counts[k] = 0;
    if (k == 0) *lossAcc = 0.0f;
}

// R9: VMEM-broadcast w rows, position-split.
// Path history: s_load (R6/R7) is OUT-OF-ORDER -> only lgkmcnt(0) full drains,
// un-pipelineable, ~30% VALUBusy. LDS broadcast (R8) delivers 16B useful per
// full wave transaction -> ~218us of LDS-pipe time (the 280us wall, 66% VALU).
// Third path: per-lane global_load_dwordx4 with identical addresses = ONE L1
// line per instruction (TA broadcast), in-order counted vmcnt -> compiler
// software-pipelines across rows. Opaque VGPR zero defeats the uniformity
// analysis that would otherwise re-select s_load. Double-buffered full rows
// (static indices only), x2 in VGPRs, ww via 1 uniform ds_read_b32/row.
// ~220 VGPR < 256 budget (waves_per_eu(2,2)); grid 512 blocks = 2/CU resident.
// FP chains token-identical to R8 -> argmin bit-exact.
#define ROWDOT(BUF, KK) do {                                                \
    float s[8];                                                             \
    _Pragma("unroll")                                                       \
    for (int i = 0; i < 8; ++i) {                                           \
        _Pragma("unroll")                                                   \
        for (int j = 0; j < 8; ++j) {                                       \
            const int d = i * 8 + j;                                        \
            float wv = F4C(BUF[d >> 2], d & 3);                             \
            if (i == 0) s[j] = __fmul_rn(x2[d], wv);  /* == fmaf(a,b,0) */  \
            else        s[j] = __fmaf_rn(x2[d], wv, s[j]);                  \
        }                                                                   \
    }                                                                       \
    float dot  = tree8(s[0], s[1], s[2], s[3], s[4], s[5], s[6], s[7]);     \
    float t    = __fadd_rn(A, wwlds[KK]);  /* (||x||^2+||w_k||^2), ref */   \
    float dist = __fadd_rn(t, -dot);       /* minus 2*x.w */                \
    if (dist < best) { best = dist; bestk = (KK); }  /* strict <: first */  \
} while (0)

extern "C" __global__ __launch_bounds__(TB)
__attribute__((amdgpu_waves_per_eu(2, 2)))
void vq_main(const float* __restrict__ x, const float* __restrict__ w,
             const float* __restrict__ ww, float* __restrict__ out,
             int* __restrict__ counts, float* __restrict__ lossAcc)
{
    __shared__ float wwlds[KCODES];            // 2048 B
    __shared__ int   hcount[KCODES];           // 2048 B

    const int tid = threadIdx.x;
    const int l   = tid & 63;                  // lane (loss reduction)
    const int n   = blockIdx.x * POSB + tid;   // my position
    const int b   = n >> 12;                   // 256 | 4096: one b per block
    const int hw  = n & 4095;

    hcount[tid]      = 0;
    hcount[tid + TB] = 0;
    wwlds[tid]       = ww[tid];                // staged once, coalesced
    wwlds[tid + TB]  = ww[tid + TB];

    // ---- prologue: my position's x into VGPRs (channel stride HW), x2 = 2x,
    // A = sum(x^2) replicating numpy pairwise_sum(64): r[j] over i ascending.
    const float* xp = x + ((size_t)b * DIM) * HW + hw;
    float x2[DIM];
    float A;
    {
        float r[8];
        #pragma unroll
        for (int i = 0; i < 8; ++i) {
            #pragma unroll
            for (int j = 0; j < 8; ++j) {
                const int d = i * 8 + j;
                float v = xp[(size_t)d * HW];
                x2[d] = v + v;                  // exact doubling
                float pp = __fmul_rn(v, v);
                r[j] = (i == 0) ? pp : __fadd_rn(r[j], pp);
            }
        }
        A = tree8(r[0], r[1], r[2], r[3], r[4], r[5], r[6], r[7]);
    }

    // encodings tile zero-fill setup (T0%4==1 -> +3 shift is 16B-aligned)
    const size_t T0 = ENC_OFF + (size_t)blockIdx.x * TILE_DW;
    float4* zs4 = reinterpret_cast<float4*>(out + T0 + 3);
    const float4 zero4 = make_float4(0.0f, 0.0f, 0.0f, 0.0f);
    if (tid < 3)  out[T0 + tid] = 0.0f;              // edge dwords 0,1,2
    if (tid == 3) out[T0 + (TILE_DW - 1)] = 0.0f;    // edge dword 131071

    __syncthreads();   // wwlds + hcount ready

    // ---- opaque VGPR zero: defeats uniform-address analysis so w-row reads
    // take the global_load (vmcnt, in-order, pipelineable) path, not s_load.
    int vz = 0;
    asm volatile("" : "+v"(vz));
    const float4* w4v = reinterpret_cast<const float4*>(w) + vz;

    float4 bufA[16], bufB[16];                 // double-buffered row (static idx)
    #pragma unroll
    for (int i = 0; i < 16; ++i) bufA[i] = w4v[i];   // preload row 0

    float best  = INFINITY;
    int   bestk = 0;

    #pragma unroll 1
    for (int k = 0; k < KCODES; k += 2) {
        {   // issue row k+1 -> bufB (overlaps ROWDOT(bufA))
            const float4* nb = w4v + ((size_t)(k + 1) << 4);
            #pragma unroll
            for (int i = 0; i < 16; ++i) bufB[i] = nb[i];
        }
        ROWDOT(bufA, k);
        if ((k & 3) == 0) {                    // 128 float4 per thread total
            const int m = (k >> 2) * TB + tid; // covers [0,32768)
            if (m < NF4) zs4[m] = zero4;       // m=32767 is the tile edge
        }
        {   // issue row k+2 -> bufA (wraps to row 0 at the tail; harmless)
            const float4* na = w4v + ((size_t)((k + 2) & (KCODES - 1)) << 4);
            #pragma unroll
            for (int i = 0; i < 16; ++i) bufA[i] = na[i];
        }
        ROWDOT(bufB, k + 1);
    }

    __syncthreads();   // zero stores drained (vmcnt(0) at barrier)

    // ---- epilogue: every thread owns one position (no merge needed)
    out[ENC_OFF + (size_t)n * KCODES + bestk] = 1.0f;   // one-hot after zeros
    atomicAdd(&hcount[bestk], 1);

    const float4* wrow = reinterpret_cast<const float4*>(w + (size_t)bestk * DIM);
    float* qo = out + ((size_t)b * DIM) * HW + hw;
    float sse = 0.0f;
    #pragma unroll
    for (int c = 0; c < 16; ++c) {
        float4 q = wrow[c];
        qo[(size_t)(4 * c + 0) * HW] = q.x;
        qo[(size_t)(4 * c + 1) * HW] = q.y;
        qo[(size_t)(4 * c + 2) * HW] = q.z;
        qo[(size_t)(4 * c + 3) * HW] = q.w;
        float e0 = q.x - 0.5f * x2[4 * c + 0]; sse = __fmaf_rn(e0, e0, sse);
        float e1 = q.y - 0.5f * x2[4 * c + 1]; sse = __fmaf_rn(e1, e1, sse);
        float e2 = q.z - 0.5f * x2[4 * c + 2]; sse = __fmaf_rn(e2, e2, sse);
        float e3 = q.w - 0.5f * x2[4 * c + 3]; sse = __fmaf_rn(e3, e3, sse);
    }
    // wave-level SSE reduction (64 lanes), one atomic per wave
    #pragma unroll
    for (int off = 32; off > 0; off >>= 1) sse += __shfl_down(sse, off);
    if (l == 0) atomicAdd(lossAcc, sse);

    __syncthreads();   // hcount atomics done

    // histogram drain
    {
        int c0 = hcount[tid];       if (c0) atomicAdd(&counts[tid], c0);
        int c1 = hcount[tid + TB];  if (c1) atomicAdd(&counts[tid + TB], c1);
    }
}

// Finalize: loss scalar + perplexity from histogram.
extern "C" __global__ __launch_bounds__(512)
void vq_finalize(const int* __restrict__ counts, const float* __restrict__ lossAcc,
                 float* __restrict__ out)
{
    __shared__ double sred[KCODES];
    const int t = threadIdx.x;                 // 512 threads
    double p = (double)counts[t] * (1.0 / (double)NPOS);
    sred[t] = -p * log(p + 1e-10);
    __syncthreads();
    for (int s = KCODES / 2; s > 0; s >>= 1) {
        if (t < s) sred[t] += sred[t + s];
        __syncthreads();
    }
    if (t == 0) {
        out[PERP_OFF] = (float)exp(sred[0]);
        out[LOSS_OFF] = 1.25f * (lossAcc[0] / 8388608.0f);
    }
}

extern "C" void kernel_launch(void* const* d_in, const int* in_sizes, int n_in,
                              void* d_out, int out_size, void* d_ws, size_t ws_size,
                              hipStream_t stream)
{
    const float* x = (const float*)d_in[0];    // [32,64,64,64] fp32
    const float* w = (const float*)d_in[1];    // [512,64] fp32
    float* out = (float*)d_out;

    float* ww      = (float*)d_ws;                         // 512 floats
    int*   counts  = (int*)((char*)d_ws + 2048);           // 512 ints
    float* lossAcc = (float*)((char*)d_ws + 4096);         // 1 float

    vq_prep<<<1, 512, 0, stream>>>(w, ww, counts, lossAcc);
    vq_main<<<NPOS / POSB, TB, 0, stream>>>(x, w, ww, out, counts, lossAcc);
    vq_finalize<<<1, 512, 0, stream>>>(counts, lossAcc, out);
}